// Round 4
// baseline (370.069 us; speedup 1.0000x reference)
//
#include <hip/hip_runtime.h>
#include <math.h>

// EuclideanCodebook: x (8,4096,256) fp32, embed (8192,256) fp32
// out = embed[argmin_k ||x - e_k||^2], first-index tie rule.
//
// R9b: identical to R9 (round-3 bench died with "MI355X container failed
// twice" = infra, no counters; kernel re-audited: barriers uniform, LDS
// 68.9KB/block, bounds OK, double-buffer logic = validated R6-R8).
//
// R9: two 512-thread blocks per CU instead of one 1024-thread block.
// Empirical register-budget law from R4-R8: 1024-thr workgroups get a hard
// 64-VGPR budget (R7/R8: VGPR_Count=64 + 64MB scratch regardless of
// amdgpu_waves_per_eu); 512-thr workgroups get 128 (R4/R5 default, R6 (1,2)).
// So: grid 512 x 512 threads, block owns 64 rows, 8 waves = 2 rowg x 4 colg.
// Per-wave structure = R7/R8 (validated absmax 0): af[2][8] register A-frags,
// single 16-col B stream via precomputed E/O swizzle bases + imm offsets,
// 2 MFMA/ks, med3 top-2, 64-stream merge (128 cands/row), exact recheck.
// LDS 67 KB/block -> 2 blocks/CU (134 KB), 16 waves/CU = 4 waves/SIMD, and
// the two blocks barrier independently so one computes while the other
// drains its global_load_lds barrier. Demand ~116 regs < 128 -> no spill.

#define DIM 256
#define KCODES 8192
#define NROWS 32768
#define TILE_CODES 64
#define NT (KCODES / TILE_CODES)   // 128
#define ROWS_PER_BLK 64

typedef _Float16 half8 __attribute__((ext_vector_type(8)));
typedef _Float16 half4_t __attribute__((ext_vector_type(4)));
typedef float f32x4 __attribute__((ext_vector_type(4)));

// ---- ws layout (bytes) ----
#define ES_OFF 0u                 // 8192*256 f16 = 4194304
#define ESQ_OFF 4194304u          // 8192 f32     = 32768
#define WS_NEED 4227072u

#define GLOAD_LDS16(gp, lp) \
    __builtin_amdgcn_global_load_lds((const __attribute__((address_space(1))) void*)(gp), \
                                     (__attribute__((address_space(3))) void*)(lp), 16, 0, 0)

// ---------------- prep: embed fp32 -> fp16 + e_sq (approx use only) ----------------
__global__ void cvt_esq(const float* __restrict__ emb, _Float16* __restrict__ Es,
                        float* __restrict__ esq) {
    const int gid = blockIdx.x * 256 + threadIdx.x;
    const int code = gid >> 2, q = gid & 3;
    const float4* src = (const float4*)(emb + (size_t)code * DIM + q * 64);
    half4_t* dst = (half4_t*)(Es + (size_t)code * DIM + q * 64);
    float s = 0.f;
#pragma unroll
    for (int i = 0; i < 16; ++i) {
        const float4 v = src[i];
        half4_t h;
        h[0] = (_Float16)v.x; h[1] = (_Float16)v.y; h[2] = (_Float16)v.z; h[3] = (_Float16)v.w;
        dst[i] = h;
        s = fmaf(v.x, v.x, s); s = fmaf(v.y, v.y, s);
        s = fmaf(v.z, v.z, s); s = fmaf(v.w, v.w, s);
    }
    s += __shfl_xor(s, 1);
    s += __shfl_xor(s, 2);
    if (q == 0) esq[code] = s;
}

// ---------------- fused: MFMA score + top-4 + exact recheck + gather ----------------
// grid 512 blocks x 512 threads (8 waves). Block owns rows [blockIdx*64, +64).
// Wave wv: rowg = wv&1 (32-row slice), colg = wv>>1 (16-col slice of 64-code tile).
// No waves_per_eu attr: 512-thr default heuristic = 128-VGPR budget (R4/R5
// evidence); demand ~116 fits. 2 blocks co-resident per CU.
__global__ __attribute__((amdgpu_flat_work_group_size(512, 512))) void vq_fused(
    const float* __restrict__ x, const _Float16* __restrict__ Es,
    const float* __restrict__ esq, const float* __restrict__ embed,
    float* __restrict__ out)
{
    __shared__ __align__(16) _Float16 Bs[2][TILE_CODES * 256];  // 2 x 32 KB
    __shared__ float top4s[ROWS_PER_BLK][4];
    __shared__ float rd[ROWS_PER_BLK][4];
    __shared__ int rk[ROWS_PER_BLK][4];
    __shared__ int win[ROWS_PER_BLK];

    const int tid = threadIdx.x;
    const int lane = tid & 63;
    const int wv = tid >> 6;        // 0..7
    const int rowg = wv & 1;        // 2 row groups x 32 rows
    const int colg = wv >> 1;       // 4 col groups x 16 cols
    const int lm = lane & 15;
    const int quad = lane >> 4;
    const int rowblk = blockIdx.x * ROWS_PER_BLK;

    // ---- A fragments register-resident (fp32 x -> fp16): 32 rows -> 64 VGPRs ----
    half8 af[2][8];
#pragma unroll
    for (int am = 0; am < 2; ++am) {
        const float* xr = x + (size_t)(rowblk + rowg * 32 + am * 16 + lm) * DIM + quad * 8;
#pragma unroll
        for (int ks = 0; ks < 8; ++ks) {
            const float4 a = *(const float4*)(xr + ks * 32);
            const float4 b = *(const float4*)(xr + ks * 32 + 4);
            half8 h;
            h[0] = (_Float16)a.x; h[1] = (_Float16)a.y; h[2] = (_Float16)a.z; h[3] = (_Float16)a.w;
            h[4] = (_Float16)b.x; h[5] = (_Float16)b.y; h[6] = (_Float16)b.z; h[7] = (_Float16)b.w;
            af[am][ks] = h;
        }
    }

    // packed (score | index in low 13 mantissa bits) top-2 per row-slot
    // (8 slots = 2 am x 4 acc-regs; single 16-col stream per wave).
    float p1[8], p2[8];
#pragma unroll
    for (int i = 0; i < 8; ++i) { p1[i] = -INFINITY; p2[i] = -INFINITY; }

    // ---- per-lane LDS read bases: addr(ks) = (ks&1 ? pO : pE) + ks*64 ----
    // chunk' = (ks*4+quad) ^ (lm&7): bit2 of chunk = ks0^(z>>2), bits0-1 = quad^(z&3)
    const char* BsB = (const char*)&Bs[0][0];
    const int z = lm & 7;
    const int cl = colg * 16 + lm;
    const int base_b = cl * 512 + (quad ^ (z & 3)) * 16;
    const int zb64 = (z >> 2) * 64;
    const char* pE0 = BsB + base_b + zb64;
    const char* pO0 = BsB + base_b - zb64;

    // staging role: wave stages codes [wv*8, wv*8+8) of each tile (4 x 1KB loads)
    const int bpos = lane & 31;
    const int cl_lo = wv * 8 + (lane >> 5);
    const _Float16* g0 = Es + (size_t)(cl_lo + 0) * 256 + (size_t)((bpos ^ ((cl_lo + 0) & 7)) * 8);
    const _Float16* g1 = Es + (size_t)(cl_lo + 2) * 256 + (size_t)((bpos ^ ((cl_lo + 2) & 7)) * 8);
    const _Float16* g2 = Es + (size_t)(cl_lo + 4) * 256 + (size_t)((bpos ^ ((cl_lo + 4) & 7)) * 8);
    const _Float16* g3 = Es + (size_t)(cl_lo + 6) * 256 + (size_t)((bpos ^ ((cl_lo + 6) & 7)) * 8);

    // prologue: stage tile 0 into buf 0
    {
        char* dst = (char*)&Bs[0][0];
        GLOAD_LDS16(g0, dst + (wv * 8 + 0) * 512);
        GLOAD_LDS16(g1, dst + (wv * 8 + 2) * 512);
        GLOAD_LDS16(g2, dst + (wv * 8 + 4) * 512);
        GLOAD_LDS16(g3, dst + (wv * 8 + 6) * 512);
    }
    g0 += TILE_CODES * 256; g1 += TILE_CODES * 256;
    g2 += TILE_CODES * 256; g3 += TILE_CODES * 256;
    const float* eptr = esq + colg * 16 + lm;
    float e_nxt = *eptr;
    __syncthreads();

    for (int nt = 0; nt < NT; ++nt) {
        const int cur = nt & 1;
        if (nt + 1 < NT) {
            char* dst = (char*)&Bs[0][0] + ((cur ^ 1) << 15);
            GLOAD_LDS16(g0, dst + (wv * 8 + 0) * 512);
            GLOAD_LDS16(g1, dst + (wv * 8 + 2) * 512);
            GLOAD_LDS16(g2, dst + (wv * 8 + 4) * 512);
            GLOAD_LDS16(g3, dst + (wv * 8 + 6) * 512);
            g0 += TILE_CODES * 256; g1 += TILE_CODES * 256;
            g2 += TILE_CODES * 256; g3 += TILE_CODES * 256;
        }
        const float e = e_nxt;
        if (nt + 1 < NT) { eptr += TILE_CODES; e_nxt = *eptr; }

        f32x4 acc0, acc1;
        {
            const float v = -0.5f * e;
            const f32x4 iv = {v, v, v, v};
            acc0 = iv; acc1 = iv;
        }
        const char* pE = pE0 + (cur << 15);
        const char* pO = pO0 + (cur << 15);
#pragma unroll
        for (int ks = 0; ks < 8; ++ks) {
            const half8 bf = *(const half8*)(((ks & 1) ? pO : pE) + ks * 64);
            acc0 = __builtin_amdgcn_mfma_f32_16x16x32_f16(af[0][ks], bf, acc0, 0, 0, 0);
            acc1 = __builtin_amdgcn_mfma_f32_16x16x32_f16(af[1][ks], bf, acc1, 0, 0, 0);
        }

        // epilogue: pack (and_or) + top-2 via med3 (p1 >= p2 invariant)
        const unsigned kk = (unsigned)(nt * TILE_CODES + colg * 16 + lm);
#pragma unroll
        for (int r = 0; r < 4; ++r) {
            {
                const float pv = __uint_as_float((__float_as_uint(acc0[r]) & 0xFFFFE000u) | kk);
                p2[r] = __builtin_amdgcn_fmed3f(p1[r], p2[r], pv);
                p1[r] = fmaxf(p1[r], pv);
            }
            {
                const float pv = __uint_as_float((__float_as_uint(acc1[r]) & 0xFFFFE000u) | kk);
                p2[4 + r] = __builtin_amdgcn_fmed3f(p1[4 + r], p2[4 + r], pv);
                p1[4 + r] = fmaxf(p1[4 + r], pv);
            }
        }

        __syncthreads();   // reads of Bs[cur] done + prefetch into cur^1 visible
    }

    // ---- merge: per row, 64 streams x top-2 = 128 packed values -> top-4 ----
    // stride 129 floats: reader banks = (tid*129+p)%32 = (tid+p)%32 -> 2-way max
    float* mb = (float*)Bs;   // [64][129] floats = 33 KB, reuses tile buffers
#pragma unroll
    for (int s = 0; s < 8; ++s) {
        const int row = rowg * 32 + (s >> 2) * 16 + quad * 4 + (s & 3);
        const int pos = (colg * 16 + lm) * 2;
        mb[row * 129 + pos] = p1[s];
        mb[row * 129 + pos + 1] = p2[s];
    }
    __syncthreads();
    if (tid < ROWS_PER_BLK) {
        float t1 = -INFINITY, t2 = -INFINITY, t3 = -INFINITY, t4 = -INFINITY;
        for (int p = 0; p < 128; ++p) {
            const float v = mb[tid * 129 + p];
            const float m1 = fminf(t1, v);
            t1 = fmaxf(t1, v);
            const float m2 = fminf(t2, m1);
            t2 = fmaxf(t2, m1);
            const float m3 = fminf(t3, m2);
            t3 = fmaxf(t3, m2);
            t4 = fmaxf(t4, m3);
        }
        top4s[tid][0] = t1; top4s[tid][1] = t2; top4s[tid][2] = t3; top4s[tid][3] = t4;
    }
    __syncthreads();

    // ---- exact fp32 recheck: 4 threads/row, 1 candidate each (tid < 256) ----
    if (tid < 4 * ROWS_PER_BLK) {
        const int row = tid >> 2;
        const int ci = tid & 3;
        const int k = (int)(__float_as_uint(top4s[row][ci]) & 8191u);
        const float4* x4 = (const float4*)(x + (size_t)(rowblk + row) * DIM);
        float cs[4];
#pragma unroll
        for (int co = 0; co < 4; ++co) {
            float s = 0.f;
            for (int c4 = 0; c4 < 16; ++c4) {
                const float4 v = x4[co * 16 + c4];
                s = fmaf(v.x, v.x, s); s = fmaf(v.y, v.y, s);
                s = fmaf(v.z, v.z, s); s = fmaf(v.w, v.w, s);
            }
            cs[co] = s;
        }
        const float xsq = ((cs[0] + cs[1]) + cs[2]) + cs[3];
        const float4* e4 = (const float4*)(embed + (size_t)k * DIM);
        float dot = 0.f, es = 0.f;
        for (int c4 = 0; c4 < 64; ++c4) {
            const float4 xv = x4[c4], evv = e4[c4];
            dot = fmaf(xv.x, evv.x, dot); dot = fmaf(xv.y, evv.y, dot);
            dot = fmaf(xv.z, evv.z, dot); dot = fmaf(xv.w, evv.w, dot);
            es = fmaf(evv.x, evv.x, es); es = fmaf(evv.y, evv.y, es);
            es = fmaf(evv.z, evv.z, es); es = fmaf(evv.w, evv.w, es);
        }
        rd[row][ci] = fmaf(-2.0f, dot, xsq) + es;   // validated rounding sequence
        rk[row][ci] = k;
    }
    __syncthreads();
    if (tid < ROWS_PER_BLK) {
        float best = rd[tid][0]; int bidx = rk[tid][0];
#pragma unroll
        for (int t = 1; t < 4; ++t) {
            const float d2 = rd[tid][t]; const int k2 = rk[tid][t];
            if (d2 < best || (d2 == best && k2 < bidx)) { best = d2; bidx = k2; }
        }
        win[tid] = bidx;
    }
    __syncthreads();

    // ---- coalesced gather (512 threads: 8 row-banks x 8 rows) ----
    {
        const int q = tid & 63;
        const int rb = tid >> 6;   // 0..7
        const float4* e4 = (const float4*)embed;
        float4* o4 = (float4*)out;
#pragma unroll
        for (int p = 0; p < 8; ++p) {
            const int r = rb + p * 8;
            const int k = win[r];
            o4[(size_t)(rowblk + r) * 64 + q] = e4[(size_t)k * 64 + q];
        }
    }
}

// ---------------- Fallback (round-1 kernel, passed absmax 0) ----------------
#define BM 64
#define BN 128
#define BC 64
#define NKT (KCODES / BN)
#define NCC (DIM / BC)

__global__ __launch_bounds__(256, 3) void vq_argmin_gather(
    const float* __restrict__ x, const float* __restrict__ embed,
    float* __restrict__ out)
{
    __shared__ __align__(16) float xs[BC * BM];
    __shared__ __align__(16) float es[BC * BN];
    const int tid = threadIdx.x;
    const int tx = tid & 15;
    const int ty = tid >> 4;
    const int row0 = blockIdx.x * BM;
    float xsq[4];
    {
        const int m = tid >> 2;
        const int quarter = tid & 3;
        const float* xr = x + (size_t)(row0 + m) * DIM + quarter * 64;
        float s = 0.f;
        for (int c = 0; c < 64; ++c) s = fmaf(xr[c], xr[c], s);
        es[tid] = s;
        __syncthreads();
#pragma unroll
        for (int i = 0; i < 4; ++i) {
            const int r = 4 * ty + i;
            xsq[i] = ((es[4*r] + es[4*r+1]) + es[4*r+2]) + es[4*r+3];
        }
        __syncthreads();
    }
    float bd[4] = {INFINITY, INFINITY, INFINITY, INFINITY};
    int bk[4] = {0, 0, 0, 0};
    for (int kt = 0; kt < NKT; ++kt) {
        const int k0 = kt * BN;
        float acc[4][8];
#pragma unroll
        for (int i = 0; i < 4; ++i)
#pragma unroll
            for (int j = 0; j < 8; ++j) acc[i][j] = 0.f;
        float e_acc = 0.f;
        for (int cc = 0; cc < NCC; ++cc) {
            __syncthreads();
            {
                const int q = tid & 15;
                const int nb = tid >> 4;
#pragma unroll
                for (int p = 0; p < 4; ++p) {
                    const int m = nb + 16 * p;
                    const float4 v = *(const float4*)(x + (size_t)(row0 + m) * DIM + cc * BC + 4 * q);
                    xs[(4*q+0)*BM+m] = v.x; xs[(4*q+1)*BM+m] = v.y;
                    xs[(4*q+2)*BM+m] = v.z; xs[(4*q+3)*BM+m] = v.w;
                }
#pragma unroll
                for (int p = 0; p < 8; ++p) {
                    const int n = nb + 16 * p;
                    const float4 v = *(const float4*)(embed + (size_t)(k0 + n) * DIM + cc * BC + 4 * q);
                    es[(4*q+0)*BN+n] = v.x; es[(4*q+1)*BN+n] = v.y;
                    es[(4*q+2)*BN+n] = v.z; es[(4*q+3)*BN+n] = v.w;
                }
            }
            __syncthreads();
            if (tid < BN) {
#pragma unroll 8
                for (int c = 0; c < BC; ++c) { const float v = es[c*BN+tid]; e_acc = fmaf(v, v, e_acc); }
            }
#pragma unroll 8
            for (int c = 0; c < BC; ++c) {
                const float4 a0 = *(const float4*)&xs[c*BM+4*ty];
                const float4 b0 = *(const float4*)&es[c*BN+4*tx];
                const float4 b1 = *(const float4*)&es[c*BN+64+4*tx];
                const float a[4] = {a0.x, a0.y, a0.z, a0.w};
                const float b[8] = {b0.x, b0.y, b0.z, b0.w, b1.x, b1.y, b1.z, b1.w};
#pragma unroll
                for (int i = 0; i < 4; ++i)
#pragma unroll
                    for (int j = 0; j < 8; ++j) acc[i][j] = fmaf(a[i], b[j], acc[i][j]);
            }
        }
        __syncthreads();
        if (tid < BN) es[tid] = e_acc;
        __syncthreads();
        float esq2[8];
#pragma unroll
        for (int j = 0; j < 4; ++j) { esq2[j] = es[4*tx+j]; esq2[4+j] = es[64+4*tx+j]; }
#pragma unroll
        for (int i = 0; i < 4; ++i)
#pragma unroll
            for (int j = 0; j < 8; ++j) {
                const float d = fmaf(-2.0f, acc[i][j], xsq[i]) + esq2[j];
                const int kk = k0 + ((j < 4) ? (4*tx+j) : (64+4*tx+(j-4)));
                if (d < bd[i]) { bd[i] = d; bk[i] = kk; }
            }
    }
    __syncthreads();
    float* red_d = xs;
    int* red_k = (int*)es;
#pragma unroll
    for (int i = 0; i < 4; ++i) { const int r = 4*ty+i; red_d[r*16+tx] = bd[i]; red_k[r*16+tx] = bk[i]; }
    __syncthreads();
    int winner = 0;
    if (tid < BM) {
        float best = red_d[tid*16]; int bidx = red_k[tid*16];
#pragma unroll
        for (int t = 1; t < 16; ++t) {
            const float d2 = red_d[tid*16+t]; const int k2 = red_k[tid*16+t];
            if (d2 < best || (d2 == best && k2 < bidx)) { best = d2; bidx = k2; }
        }
        winner = bidx;
    }
    __syncthreads();
    int* wn = (int*)xs;
    if (tid < BM) wn[tid] = winner;
    __syncthreads();
    {
        const int q = tid & 63;
        const int rb = tid >> 6;
        const float4* e4 = (const float4*)embed;
        float4* o4 = (float4*)out;
#pragma unroll
        for (int p = 0; p < 16; ++p) {
            const int rr = rb + 4 * p;
            const int k = wn[rr];
            o4[(size_t)(row0 + rr) * 64 + q] = e4[(size_t)k * 64 + q];
        }
    }
}

extern "C" void kernel_launch(void* const* d_in, const int* in_sizes, int n_in,
                              void* d_out, int out_size, void* d_ws, size_t ws_size,
                              hipStream_t stream) {
    const float* x = (const float*)d_in[0];
    const float* embed = (const float*)d_in[1];
    float* out = (float*)d_out;

    if (ws_size < (size_t)WS_NEED) {
        hipLaunchKernelGGL(vq_argmin_gather, dim3(NROWS / BM), dim3(256), 0, stream, x, embed, out);
        return;
    }
    char* ws = (char*)d_ws;
    _Float16* Es = (_Float16*)(ws + ES_OFF);
    float* esq = (float*)(ws + ESQ_OFF);

    hipLaunchKernelGGL(cvt_esq, dim3(128), dim3(256), 0, stream, embed, Es, esq);
    hipLaunchKernelGGL(vq_fused, dim3(NROWS / ROWS_PER_BLK), dim3(512), 0, stream, x, Es, esq, embed, out);
}

// Round 5
// 329.939 us; speedup vs baseline: 1.1216x; 1.1216x over previous
//
#include <hip/hip_runtime.h>
#include <math.h>

// EuclideanCodebook: x (8,4096,256) fp32, embed (8192,256) fp32
// out = embed[argmin_k ||x - e_k||^2], first-index tie rule.
//
// R10: R9b with block LDS trimmed 67.5 KB -> exactly 64 KB so TWO 512-thread
// blocks co-reside per CU. R9b evidence: VGPR_Count=128, no scratch (budget
// law holds for 512-thr), but Occupancy 23% = 1 block/CU and dur 310us =
// 2 x 155us strictly serialized blocks. Hypothesis: effective per-CU LDS
// pool for placement is 128 KB, and 2 x 69120 B > 128 KB blocked residency.
// Fix: overlay the post-K-loop aux arrays (top4s/rd/rk/win) into the Bs
// arena (merge buffer mb already lived there): static LDS = 65536 B exactly.
// Layout inside the 64 KB arena after the K-loop: mb [64][129]f = 33024 B at
// +0, top4s at +40960 (1024), rd at +41984 (1024), rk at +43008 (1024),
// win at +44032 (256). No overlap; all uses are after the final K-loop
// barrier. K-loop, staging, swizzle, med3 top-2, exact recheck, gather are
// bit-identical to R9b (absmax 0).
// Expected: 2 blocks/CU -> 16 waves/CU (4/SIMD); one block computes while
// the other drains its global_load_lds barrier.

#define DIM 256
#define KCODES 8192
#define NROWS 32768
#define TILE_CODES 64
#define NT (KCODES / TILE_CODES)   // 128
#define ROWS_PER_BLK 64

typedef _Float16 half8 __attribute__((ext_vector_type(8)));
typedef _Float16 half4_t __attribute__((ext_vector_type(4)));
typedef float f32x4 __attribute__((ext_vector_type(4)));

// ---- ws layout (bytes) ----
#define ES_OFF 0u                 // 8192*256 f16 = 4194304
#define ESQ_OFF 4194304u          // 8192 f32     = 32768
#define WS_NEED 4227072u

#define GLOAD_LDS16(gp, lp) \
    __builtin_amdgcn_global_load_lds((const __attribute__((address_space(1))) void*)(gp), \
                                     (__attribute__((address_space(3))) void*)(lp), 16, 0, 0)

// ---------------- prep: embed fp32 -> fp16 + e_sq (approx use only) ----------------
__global__ void cvt_esq(const float* __restrict__ emb, _Float16* __restrict__ Es,
                        float* __restrict__ esq) {
    const int gid = blockIdx.x * 256 + threadIdx.x;
    const int code = gid >> 2, q = gid & 3;
    const float4* src = (const float4*)(emb + (size_t)code * DIM + q * 64);
    half4_t* dst = (half4_t*)(Es + (size_t)code * DIM + q * 64);
    float s = 0.f;
#pragma unroll
    for (int i = 0; i < 16; ++i) {
        const float4 v = src[i];
        half4_t h;
        h[0] = (_Float16)v.x; h[1] = (_Float16)v.y; h[2] = (_Float16)v.z; h[3] = (_Float16)v.w;
        dst[i] = h;
        s = fmaf(v.x, v.x, s); s = fmaf(v.y, v.y, s);
        s = fmaf(v.z, v.z, s); s = fmaf(v.w, v.w, s);
    }
    s += __shfl_xor(s, 1);
    s += __shfl_xor(s, 2);
    if (q == 0) esq[code] = s;
}

// ---------------- fused: MFMA score + top-4 + exact recheck + gather ----------------
// grid 512 blocks x 512 threads (8 waves). Block owns rows [blockIdx*64, +64).
// Wave wv: rowg = wv&1 (32-row slice), colg = wv>>1 (16-col slice of 64-code tile).
// Static LDS exactly 65536 B -> 2 blocks/CU at a 128 KB placement pool.
__global__ __attribute__((amdgpu_flat_work_group_size(512, 512))) void vq_fused(
    const float* __restrict__ x, const _Float16* __restrict__ Es,
    const float* __restrict__ esq, const float* __restrict__ embed,
    float* __restrict__ out)
{
    __shared__ __align__(16) char smem[65536];   // 2 x 32 KB tile buffers + overlays

    const int tid = threadIdx.x;
    const int lane = tid & 63;
    const int wv = tid >> 6;        // 0..7
    const int rowg = wv & 1;        // 2 row groups x 32 rows
    const int colg = wv >> 1;       // 4 col groups x 16 cols
    const int lm = lane & 15;
    const int quad = lane >> 4;
    const int rowblk = blockIdx.x * ROWS_PER_BLK;

    // post-K-loop overlays inside the arena
    float* mb = (float*)smem;                          // [64][129] = 33024 B
    float (*top4s)[4] = (float (*)[4])(smem + 40960);  // 1024 B
    float (*rd)[4] = (float (*)[4])(smem + 41984);     // 1024 B
    int (*rk)[4] = (int (*)[4])(smem + 43008);         // 1024 B
    int* win = (int*)(smem + 44032);                   // 256 B

    // ---- A fragments register-resident (fp32 x -> fp16): 32 rows -> 64 VGPRs ----
    half8 af[2][8];
#pragma unroll
    for (int am = 0; am < 2; ++am) {
        const float* xr = x + (size_t)(rowblk + rowg * 32 + am * 16 + lm) * DIM + quad * 8;
#pragma unroll
        for (int ks = 0; ks < 8; ++ks) {
            const float4 a = *(const float4*)(xr + ks * 32);
            const float4 b = *(const float4*)(xr + ks * 32 + 4);
            half8 h;
            h[0] = (_Float16)a.x; h[1] = (_Float16)a.y; h[2] = (_Float16)a.z; h[3] = (_Float16)a.w;
            h[4] = (_Float16)b.x; h[5] = (_Float16)b.y; h[6] = (_Float16)b.z; h[7] = (_Float16)b.w;
            af[am][ks] = h;
        }
    }

    // packed (score | index in low 13 mantissa bits) top-2 per row-slot
    // (8 slots = 2 am x 4 acc-regs; single 16-col stream per wave).
    float p1[8], p2[8];
#pragma unroll
    for (int i = 0; i < 8; ++i) { p1[i] = -INFINITY; p2[i] = -INFINITY; }

    // ---- per-lane LDS read bases: addr(ks) = (ks&1 ? pO : pE) + ks*64 ----
    // chunk' = (ks*4+quad) ^ (lm&7): bit2 of chunk = ks0^(z>>2), bits0-1 = quad^(z&3)
    const char* BsB = (const char*)smem;
    const int z = lm & 7;
    const int cl = colg * 16 + lm;
    const int base_b = cl * 512 + (quad ^ (z & 3)) * 16;
    const int zb64 = (z >> 2) * 64;
    const char* pE0 = BsB + base_b + zb64;
    const char* pO0 = BsB + base_b - zb64;

    // staging role: wave stages codes [wv*8, wv*8+8) of each tile (4 x 1KB loads)
    const int bpos = lane & 31;
    const int cl_lo = wv * 8 + (lane >> 5);
    const _Float16* g0 = Es + (size_t)(cl_lo + 0) * 256 + (size_t)((bpos ^ ((cl_lo + 0) & 7)) * 8);
    const _Float16* g1 = Es + (size_t)(cl_lo + 2) * 256 + (size_t)((bpos ^ ((cl_lo + 2) & 7)) * 8);
    const _Float16* g2 = Es + (size_t)(cl_lo + 4) * 256 + (size_t)((bpos ^ ((cl_lo + 4) & 7)) * 8);
    const _Float16* g3 = Es + (size_t)(cl_lo + 6) * 256 + (size_t)((bpos ^ ((cl_lo + 6) & 7)) * 8);

    // prologue: stage tile 0 into buf 0
    {
        char* dst = smem;
        GLOAD_LDS16(g0, dst + (wv * 8 + 0) * 512);
        GLOAD_LDS16(g1, dst + (wv * 8 + 2) * 512);
        GLOAD_LDS16(g2, dst + (wv * 8 + 4) * 512);
        GLOAD_LDS16(g3, dst + (wv * 8 + 6) * 512);
    }
    g0 += TILE_CODES * 256; g1 += TILE_CODES * 256;
    g2 += TILE_CODES * 256; g3 += TILE_CODES * 256;
    const float* eptr = esq + colg * 16 + lm;
    float e_nxt = *eptr;
    __syncthreads();

    for (int nt = 0; nt < NT; ++nt) {
        const int cur = nt & 1;
        if (nt + 1 < NT) {
            char* dst = smem + ((cur ^ 1) << 15);
            GLOAD_LDS16(g0, dst + (wv * 8 + 0) * 512);
            GLOAD_LDS16(g1, dst + (wv * 8 + 2) * 512);
            GLOAD_LDS16(g2, dst + (wv * 8 + 4) * 512);
            GLOAD_LDS16(g3, dst + (wv * 8 + 6) * 512);
            g0 += TILE_CODES * 256; g1 += TILE_CODES * 256;
            g2 += TILE_CODES * 256; g3 += TILE_CODES * 256;
        }
        const float e = e_nxt;
        if (nt + 1 < NT) { eptr += TILE_CODES; e_nxt = *eptr; }

        f32x4 acc0, acc1;
        {
            const float v = -0.5f * e;
            const f32x4 iv = {v, v, v, v};
            acc0 = iv; acc1 = iv;
        }
        const char* pE = pE0 + (cur << 15);
        const char* pO = pO0 + (cur << 15);
#pragma unroll
        for (int ks = 0; ks < 8; ++ks) {
            const half8 bf = *(const half8*)(((ks & 1) ? pO : pE) + ks * 64);
            acc0 = __builtin_amdgcn_mfma_f32_16x16x32_f16(af[0][ks], bf, acc0, 0, 0, 0);
            acc1 = __builtin_amdgcn_mfma_f32_16x16x32_f16(af[1][ks], bf, acc1, 0, 0, 0);
        }

        // epilogue: pack (and_or) + top-2 via med3 (p1 >= p2 invariant)
        const unsigned kk = (unsigned)(nt * TILE_CODES + colg * 16 + lm);
#pragma unroll
        for (int r = 0; r < 4; ++r) {
            {
                const float pv = __uint_as_float((__float_as_uint(acc0[r]) & 0xFFFFE000u) | kk);
                p2[r] = __builtin_amdgcn_fmed3f(p1[r], p2[r], pv);
                p1[r] = fmaxf(p1[r], pv);
            }
            {
                const float pv = __uint_as_float((__float_as_uint(acc1[r]) & 0xFFFFE000u) | kk);
                p2[4 + r] = __builtin_amdgcn_fmed3f(p1[4 + r], p2[4 + r], pv);
                p1[4 + r] = fmaxf(p1[4 + r], pv);
            }
        }

        __syncthreads();   // reads of Bs[cur] done + prefetch into cur^1 visible
    }

    // ---- merge: per row, 64 streams x top-2 = 128 packed values -> top-4 ----
    // stride 129 floats: reader banks = (tid*129+p)%32 = (tid+p)%32 -> 2-way max
#pragma unroll
    for (int s = 0; s < 8; ++s) {
        const int row = rowg * 32 + (s >> 2) * 16 + quad * 4 + (s & 3);
        const int pos = (colg * 16 + lm) * 2;
        mb[row * 129 + pos] = p1[s];
        mb[row * 129 + pos + 1] = p2[s];
    }
    __syncthreads();
    if (tid < ROWS_PER_BLK) {
        float t1 = -INFINITY, t2 = -INFINITY, t3 = -INFINITY, t4 = -INFINITY;
        for (int p = 0; p < 128; ++p) {
            const float v = mb[tid * 129 + p];
            const float m1 = fminf(t1, v);
            t1 = fmaxf(t1, v);
            const float m2 = fminf(t2, m1);
            t2 = fmaxf(t2, m1);
            const float m3 = fminf(t3, m2);
            t3 = fmaxf(t3, m2);
            t4 = fmaxf(t4, m3);
        }
        top4s[tid][0] = t1; top4s[tid][1] = t2; top4s[tid][2] = t3; top4s[tid][3] = t4;
    }
    __syncthreads();

    // ---- exact fp32 recheck: 4 threads/row, 1 candidate each (tid < 256) ----
    if (tid < 4 * ROWS_PER_BLK) {
        const int row = tid >> 2;
        const int ci = tid & 3;
        const int k = (int)(__float_as_uint(top4s[row][ci]) & 8191u);
        const float4* x4 = (const float4*)(x + (size_t)(rowblk + row) * DIM);
        float cs[4];
#pragma unroll
        for (int co = 0; co < 4; ++co) {
            float s = 0.f;
            for (int c4 = 0; c4 < 16; ++c4) {
                const float4 v = x4[co * 16 + c4];
                s = fmaf(v.x, v.x, s); s = fmaf(v.y, v.y, s);
                s = fmaf(v.z, v.z, s); s = fmaf(v.w, v.w, s);
            }
            cs[co] = s;
        }
        const float xsq = ((cs[0] + cs[1]) + cs[2]) + cs[3];
        const float4* e4 = (const float4*)(embed + (size_t)k * DIM);
        float dot = 0.f, es = 0.f;
        for (int c4 = 0; c4 < 64; ++c4) {
            const float4 xv = x4[c4], evv = e4[c4];
            dot = fmaf(xv.x, evv.x, dot); dot = fmaf(xv.y, evv.y, dot);
            dot = fmaf(xv.z, evv.z, dot); dot = fmaf(xv.w, evv.w, dot);
            es = fmaf(evv.x, evv.x, es); es = fmaf(evv.y, evv.y, es);
            es = fmaf(evv.z, evv.z, es); es = fmaf(evv.w, evv.w, es);
        }
        rd[row][ci] = fmaf(-2.0f, dot, xsq) + es;   // validated rounding sequence
        rk[row][ci] = k;
    }
    __syncthreads();
    if (tid < ROWS_PER_BLK) {
        float best = rd[tid][0]; int bidx = rk[tid][0];
#pragma unroll
        for (int t = 1; t < 4; ++t) {
            const float d2 = rd[tid][t]; const int k2 = rk[tid][t];
            if (d2 < best || (d2 == best && k2 < bidx)) { best = d2; bidx = k2; }
        }
        win[tid] = bidx;
    }
    __syncthreads();

    // ---- coalesced gather (512 threads: 8 row-banks x 8 rows) ----
    {
        const int q = tid & 63;
        const int rb = tid >> 6;   // 0..7
        const float4* e4 = (const float4*)embed;
        float4* o4 = (float4*)out;
#pragma unroll
        for (int p = 0; p < 8; ++p) {
            const int r = rb + p * 8;
            const int k = win[r];
            o4[(size_t)(rowblk + r) * 64 + q] = e4[(size_t)k * 64 + q];
        }
    }
}

// ---------------- Fallback (round-1 kernel, passed absmax 0) ----------------
#define BM 64
#define BN 128
#define BC 64
#define NKT (KCODES / BN)
#define NCC (DIM / BC)

__global__ __launch_bounds__(256, 3) void vq_argmin_gather(
    const float* __restrict__ x, const float* __restrict__ embed,
    float* __restrict__ out)
{
    __shared__ __align__(16) float xs[BC * BM];
    __shared__ __align__(16) float es[BC * BN];
    const int tid = threadIdx.x;
    const int tx = tid & 15;
    const int ty = tid >> 4;
    const int row0 = blockIdx.x * BM;
    float xsq[4];
    {
        const int m = tid >> 2;
        const int quarter = tid & 3;
        const float* xr = x + (size_t)(row0 + m) * DIM + quarter * 64;
        float s = 0.f;
        for (int c = 0; c < 64; ++c) s = fmaf(xr[c], xr[c], s);
        es[tid] = s;
        __syncthreads();
#pragma unroll
        for (int i = 0; i < 4; ++i) {
            const int r = 4 * ty + i;
            xsq[i] = ((es[4*r] + es[4*r+1]) + es[4*r+2]) + es[4*r+3];
        }
        __syncthreads();
    }
    float bd[4] = {INFINITY, INFINITY, INFINITY, INFINITY};
    int bk[4] = {0, 0, 0, 0};
    for (int kt = 0; kt < NKT; ++kt) {
        const int k0 = kt * BN;
        float acc[4][8];
#pragma unroll
        for (int i = 0; i < 4; ++i)
#pragma unroll
            for (int j = 0; j < 8; ++j) acc[i][j] = 0.f;
        float e_acc = 0.f;
        for (int cc = 0; cc < NCC; ++cc) {
            __syncthreads();
            {
                const int q = tid & 15;
                const int nb = tid >> 4;
#pragma unroll
                for (int p = 0; p < 4; ++p) {
                    const int m = nb + 16 * p;
                    const float4 v = *(const float4*)(x + (size_t)(row0 + m) * DIM + cc * BC + 4 * q);
                    xs[(4*q+0)*BM+m] = v.x; xs[(4*q+1)*BM+m] = v.y;
                    xs[(4*q+2)*BM+m] = v.z; xs[(4*q+3)*BM+m] = v.w;
                }
#pragma unroll
                for (int p = 0; p < 8; ++p) {
                    const int n = nb + 16 * p;
                    const float4 v = *(const float4*)(embed + (size_t)(k0 + n) * DIM + cc * BC + 4 * q);
                    es[(4*q+0)*BN+n] = v.x; es[(4*q+1)*BN+n] = v.y;
                    es[(4*q+2)*BN+n] = v.z; es[(4*q+3)*BN+n] = v.w;
                }
            }
            __syncthreads();
            if (tid < BN) {
#pragma unroll 8
                for (int c = 0; c < BC; ++c) { const float v = es[c*BN+tid]; e_acc = fmaf(v, v, e_acc); }
            }
#pragma unroll 8
            for (int c = 0; c < BC; ++c) {
                const float4 a0 = *(const float4*)&xs[c*BM+4*ty];
                const float4 b0 = *(const float4*)&es[c*BN+4*tx];
                const float4 b1 = *(const float4*)&es[c*BN+64+4*tx];
                const float a[4] = {a0.x, a0.y, a0.z, a0.w};
                const float b[8] = {b0.x, b0.y, b0.z, b0.w, b1.x, b1.y, b1.z, b1.w};
#pragma unroll
                for (int i = 0; i < 4; ++i)
#pragma unroll
                    for (int j = 0; j < 8; ++j) acc[i][j] = fmaf(a[i], b[j], acc[i][j]);
            }
        }
        __syncthreads();
        if (tid < BN) es[tid] = e_acc;
        __syncthreads();
        float esq2[8];
#pragma unroll
        for (int j = 0; j < 4; ++j) { esq2[j] = es[4*tx+j]; esq2[4+j] = es[64+4*tx+j]; }
#pragma unroll
        for (int i = 0; i < 4; ++i)
#pragma unroll
            for (int j = 0; j < 8; ++j) {
                const float d = fmaf(-2.0f, acc[i][j], xsq[i]) + esq2[j];
                const int kk = k0 + ((j < 4) ? (4*tx+j) : (64+4*tx+(j-4)));
                if (d < bd[i]) { bd[i] = d; bk[i] = kk; }
            }
    }
    __syncthreads();
    float* red_d = xs;
    int* red_k = (int*)es;
#pragma unroll
    for (int i = 0; i < 4; ++i) { const int r = 4*ty+i; red_d[r*16+tx] = bd[i]; red_k[r*16+tx] = bk[i]; }
    __syncthreads();
    int winner = 0;
    if (tid < BM) {
        float best = red_d[tid*16]; int bidx = red_k[tid*16];
#pragma unroll
        for (int t = 1; t < 16; ++t) {
            const float d2 = red_d[tid*16+t]; const int k2 = red_k[tid*16+t];
            if (d2 < best || (d2 == best && k2 < bidx)) { best = d2; bidx = k2; }
        }
        winner = bidx;
    }
    __syncthreads();
    int* wn = (int*)xs;
    if (tid < BM) wn[tid] = winner;
    __syncthreads();
    {
        const int q = tid & 63;
        const int rb = tid >> 6;
        const float4* e4 = (const float4*)embed;
        float4* o4 = (float4*)out;
#pragma unroll
        for (int p = 0; p < 16; ++p) {
            const int rr = rb + 4 * p;
            const int k = wn[rr];
            o4[(size_t)(row0 + rr) * 64 + q] = e4[(size_t)k * 64 + q];
        }
    }
}

extern "C" void kernel_launch(void* const* d_in, const int* in_sizes, int n_in,
                              void* d_out, int out_size, void* d_ws, size_t ws_size,
                              hipStream_t stream) {
    const float* x = (const float*)d_in[0];
    const float* embed = (const float*)d_in[1];
    float* out = (float*)d_out;

    if (ws_size < (size_t)WS_NEED) {
        hipLaunchKernelGGL(vq_argmin_gather, dim3(NROWS / BM), dim3(256), 0, stream, x, embed, out);
        return;
    }
    char* ws = (char*)d_ws;
    _Float16* Es = (_Float16*)(ws + ES_OFF);
    float* esq = (float*)(ws + ESQ_OFF);

    hipLaunchKernelGGL(cvt_esq, dim3(128), dim3(256), 0, stream, embed, Es, esq);
    hipLaunchKernelGGL(vq_fused, dim3(NROWS / ROWS_PER_BLK), dim3(512), 0, stream, x, Es, esq, embed, out);
}

// Round 6
// 256.027 us; speedup vs baseline: 1.4454x; 1.2887x over previous
//
#include <hip/hip_runtime.h>
#include <math.h>

// EuclideanCodebook: x (8,4096,256) fp32, embed (8192,256) fp32
// out = embed[argmin_k ||x - e_k||^2], first-index tie rule.
//
// R11: R6 geometry (256 blocks x 512 thr, 128 rows/block, 8 waves = 4 rowg x
// 2 colg, waves_per_eu(1,2) -> 256-VGPR budget, no spill) with the barrier
// drain removed. Evidence: R7 at 45% occupancy ran the same 238us as R6 at
// 23% -> the cost is occupancy-INVARIANT. 233us/128 tiles = 4370 cyc/tile vs
// ~2000 static work: the difference is __syncthreads' implied
// s_waitcnt vmcnt(0) draining the global_load_lds queue every tile.
// Fix (T3/T4, m201/m218 pattern): 4 LDS buffers (128 KB arena), prefetch 3
// tiles ahead, per-tile `s_waitcnt vmcnt(12)` + raw s_barrier (never 0 in
// the loop; tail peel 12/12/6/0). Packet = 4 global_load_lds + 2 esq loads;
// esq values ride in static-named regs via unroll-4 (exact vmcnt counting).
// Buffer WAR safe: a buffer's readers consume (lgkm-drain) before the
// barrier that precedes its overwrite 4 tiles later. Arithmetic/selection/
// recheck/gather bit-identical to R6 (absmax 0).

#define DIM 256
#define KCODES 8192
#define NROWS 32768
#define TILE_CODES 64
#define NT (KCODES / TILE_CODES)   // 128

typedef _Float16 half8 __attribute__((ext_vector_type(8)));
typedef _Float16 half4_t __attribute__((ext_vector_type(4)));
typedef float f32x4 __attribute__((ext_vector_type(4)));

// ---- ws layout (bytes) ----
#define ES_OFF 0u                 // 8192*256 f16 = 4194304
#define ESQ_OFF 4194304u          // 8192 f32     = 32768
#define WS_NEED 4227072u

#define GLOAD_LDS16(gp, lp) \
    __builtin_amdgcn_global_load_lds((const __attribute__((address_space(1))) void*)(gp), \
                                     (__attribute__((address_space(3))) void*)(lp), 16, 0, 0)

// ---------------- prep: embed fp32 -> fp16 + e_sq (approx use only) ----------------
__global__ void cvt_esq(const float* __restrict__ emb, _Float16* __restrict__ Es,
                        float* __restrict__ esq) {
    const int gid = blockIdx.x * 256 + threadIdx.x;
    const int code = gid >> 2, q = gid & 3;
    const float4* src = (const float4*)(emb + (size_t)code * DIM + q * 64);
    half4_t* dst = (half4_t*)(Es + (size_t)code * DIM + q * 64);
    float s = 0.f;
#pragma unroll
    for (int i = 0; i < 16; ++i) {
        const float4 v = src[i];
        half4_t h;
        h[0] = (_Float16)v.x; h[1] = (_Float16)v.y; h[2] = (_Float16)v.z; h[3] = (_Float16)v.w;
        dst[i] = h;
        s = fmaf(v.x, v.x, s); s = fmaf(v.y, v.y, s);
        s = fmaf(v.z, v.z, s); s = fmaf(v.w, v.w, s);
    }
    s += __shfl_xor(s, 1);
    s += __shfl_xor(s, 2);
    if (q == 0) esq[code] = s;
}

// ---------------- fused: MFMA score + top-4 + exact recheck + gather ----------------
// grid 256 blocks x 512 threads (8 waves). Block owns rows [blockIdx*128, +128).
// Wave wv: rowg = wv&3 (32-row slice), colg = wv>>2 (32-col slice of 64-code tile).
__global__ __attribute__((amdgpu_flat_work_group_size(512, 512)))
__attribute__((amdgpu_waves_per_eu(1, 2))) void vq_fused(
    const float* __restrict__ x, const _Float16* __restrict__ Es,
    const float* __restrict__ esq, const float* __restrict__ embed,
    float* __restrict__ out)
{
    __shared__ __align__(16) char arena[131072];   // 4 x 32 KB tile buffers + overlays

    const int tid = threadIdx.x;
    const int lane = tid & 63;
    const int wv = tid >> 6;        // 0..7
    const int rowg = wv & 3;        // 4 row groups x 32 rows
    const int colg = wv >> 2;       // 2 col groups x 32 cols
    const int lm = lane & 15;
    const int quad = lane >> 4;
    const int rowblk = blockIdx.x * 128;

    // post-K-loop overlays inside the arena (all uses after the post-loop barrier)
    float* mb = (float*)arena;                          // [128][65] f = 33280 B
    float (*top4s)[4] = (float (*)[4])(arena + 34816);  // 2048 B
    float (*rd)[4] = (float (*)[4])(arena + 36864);     // 2048 B
    int (*rk)[4] = (int (*)[4])(arena + 38912);         // 2048 B
    int* win = (int*)(arena + 40960);                   // 512 B

    // ---- A fragments register-resident (fp32 x -> fp16): 32 rows -> 64 VGPRs ----
    half8 af[2][8];
#pragma unroll
    for (int am = 0; am < 2; ++am) {
        const float* xr = x + (size_t)(rowblk + rowg * 32 + am * 16 + lm) * DIM + quad * 8;
#pragma unroll
        for (int ks = 0; ks < 8; ++ks) {
            const float4 a = *(const float4*)(xr + ks * 32);
            const float4 b = *(const float4*)(xr + ks * 32 + 4);
            half8 h;
            h[0] = (_Float16)a.x; h[1] = (_Float16)a.y; h[2] = (_Float16)a.z; h[3] = (_Float16)a.w;
            h[4] = (_Float16)b.x; h[5] = (_Float16)b.y; h[6] = (_Float16)b.z; h[7] = (_Float16)b.w;
            af[am][ks] = h;
        }
    }

    // packed (score | index in low 13 mantissa bits) top-2 per row-slot
    float p1[8], p2[8];
#pragma unroll
    for (int i = 0; i < 8; ++i) { p1[i] = -INFINITY; p2[i] = -INFINITY; }

    // staging role: wave stages codes [wv*8, wv*8+8) of each tile (4 x 1KB loads)
    const int bpos = lane & 31;
    const int cl_lo = wv * 8 + (lane >> 5);
    const _Float16* g0 = Es + (size_t)(cl_lo + 0) * 256 + (size_t)((bpos ^ ((cl_lo + 0) & 7)) * 8);
    const _Float16* g1 = Es + (size_t)(cl_lo + 2) * 256 + (size_t)((bpos ^ ((cl_lo + 2) & 7)) * 8);
    const _Float16* g2 = Es + (size_t)(cl_lo + 4) * 256 + (size_t)((bpos ^ ((cl_lo + 4) & 7)) * 8);
    const _Float16* g3 = Es + (size_t)(cl_lo + 6) * 256 + (size_t)((bpos ^ ((cl_lo + 6) & 7)) * 8);

    float ea0, eb0, ea1, eb1, ea2, eb2, ea3, eb3;

    // packet = 4 global_load_lds (1 KB each) + 2 esq loads -> 6 VMEM ops, in order
#define ISSUE_PKT(TT3, BUFW, EAW, EBW) do {                                   \
        char* dsti_ = arena + (BUFW) * 32768;                                 \
        GLOAD_LDS16(g0, dsti_ + (wv * 8 + 0) * 512);                          \
        GLOAD_LDS16(g1, dsti_ + (wv * 8 + 2) * 512);                          \
        GLOAD_LDS16(g2, dsti_ + (wv * 8 + 4) * 512);                          \
        GLOAD_LDS16(g3, dsti_ + (wv * 8 + 6) * 512);                          \
        g0 += TILE_CODES * 256; g1 += TILE_CODES * 256;                       \
        g2 += TILE_CODES * 256; g3 += TILE_CODES * 256;                       \
        const float* ep_ = esq + (size_t)(TT3) * TILE_CODES + colg * 32 + lm; \
        EAW = ep_[0]; EBW = ep_[16];                                          \
    } while (0)

#define COMPUTE_TILE(TT, Q, EAR, EBR) do {                                               \
        f32x4 acc00, acc01, acc10, acc11;                                                \
        { const float v0_ = -0.5f * (EAR), v1_ = -0.5f * (EBR);                          \
          const f32x4 i0_ = {v0_, v0_, v0_, v0_};                                        \
          const f32x4 i1_ = {v1_, v1_, v1_, v1_};                                        \
          acc00 = i0_; acc10 = i0_; acc01 = i1_; acc11 = i1_; }                          \
        const _Float16* Bq_ = (const _Float16*)(arena + (Q) * 32768);                    \
        _Pragma("unroll")                                                                \
        for (int ks = 0; ks < 8; ++ks) {                                                 \
            const int sw_ = ((ks * 4 + quad) ^ (lm & 7)) * 8;                            \
            const half8 bf0_ = *(const half8*)(&Bq_[(colg * 32 + lm) * 256 + sw_]);      \
            const half8 bf1_ = *(const half8*)(&Bq_[(colg * 32 + 16 + lm) * 256 + sw_]); \
            acc00 = __builtin_amdgcn_mfma_f32_16x16x32_f16(af[0][ks], bf0_, acc00, 0, 0, 0); \
            acc01 = __builtin_amdgcn_mfma_f32_16x16x32_f16(af[0][ks], bf1_, acc01, 0, 0, 0); \
            acc10 = __builtin_amdgcn_mfma_f32_16x16x32_f16(af[1][ks], bf0_, acc10, 0, 0, 0); \
            acc11 = __builtin_amdgcn_mfma_f32_16x16x32_f16(af[1][ks], bf1_, acc11, 0, 0, 0); \
        }                                                                                \
        const unsigned kk0_ = (unsigned)((TT) * TILE_CODES + colg * 32 + lm);            \
        const unsigned kk1_ = kk0_ + 16u;                                                \
        _Pragma("unroll")                                                                \
        for (int r = 0; r < 4; ++r) {                                                    \
            { const float pv = __uint_as_float((__float_as_uint(acc00[r]) & 0xFFFFE000u) | kk0_); \
              p2[r] = __builtin_amdgcn_fmed3f(p1[r], p2[r], pv); p1[r] = fmaxf(p1[r], pv); }      \
            { const float pv = __uint_as_float((__float_as_uint(acc01[r]) & 0xFFFFE000u) | kk1_); \
              p2[r] = __builtin_amdgcn_fmed3f(p1[r], p2[r], pv); p1[r] = fmaxf(p1[r], pv); }      \
            { const float pv = __uint_as_float((__float_as_uint(acc10[r]) & 0xFFFFE000u) | kk0_); \
              p2[4+r] = __builtin_amdgcn_fmed3f(p1[4+r], p2[4+r], pv); p1[4+r] = fmaxf(p1[4+r], pv); } \
            { const float pv = __uint_as_float((__float_as_uint(acc11[r]) & 0xFFFFE000u) | kk1_); \
              p2[4+r] = __builtin_amdgcn_fmed3f(p1[4+r], p2[4+r], pv); p1[4+r] = fmaxf(p1[4+r], pv); } \
        }                                                                                \
    } while (0)

    // PHASE: counted-vmcnt (never 0 mid-loop) + raw barrier, then issue, then compute.
#define PHASE(TT, Q, DOISSUE, VMSTR, EAR, EBR, EAW, EBW) do {       \
        asm volatile("s_waitcnt vmcnt(" VMSTR ")" ::: "memory");    \
        __builtin_amdgcn_s_barrier();                               \
        if (DOISSUE) ISSUE_PKT((TT) + 3, ((Q) + 3) & 3, EAW, EBW);  \
        COMPUTE_TILE((TT), (Q), EAR, EBR);                          \
    } while (0)

    // prologue: packets for tiles 0,1,2 into bufs 0,1,2 (18 VMEM outstanding)
    ISSUE_PKT(0, 0, ea0, eb0);
    ISSUE_PKT(1, 1, ea1, eb1);
    ISSUE_PKT(2, 2, ea2, eb2);

    // main loop: tiles 0..123, 4 phases per macro-iter (buffer & e-regs static)
    for (int t = 0; t < NT - 4; t += 4) {
        PHASE(t + 0, 0, 1, "12", ea0, eb0, ea3, eb3);
        PHASE(t + 1, 1, 1, "12", ea1, eb1, ea0, eb0);
        PHASE(t + 2, 2, 1, "12", ea2, eb2, ea1, eb1);
        PHASE(t + 3, 3, 1, "12", ea3, eb3, ea2, eb2);
    }
    // peel: tiles 124..127 (packet 127 issued at phase 124; waits 12/12/6/0)
    PHASE(NT - 4, 0, 1, "12", ea0, eb0, ea3, eb3);
    PHASE(NT - 3, 1, 0, "12", ea1, eb1, ea0, eb0);
    PHASE(NT - 2, 2, 0, "6",  ea2, eb2, ea0, eb0);
    PHASE(NT - 1, 3, 0, "0",  ea3, eb3, ea0, eb0);

    __syncthreads();   // full drain once; arena becomes merge scratch

    // ---- merge: per row, 32 streams x top-2 = 64 packed values -> top-4 ----
    // stride 65 floats: reader banks = (tid*65+p)%32 = (tid+p)%32 -> conflict-free
#pragma unroll
    for (int s = 0; s < 8; ++s) {
        const int row = rowg * 32 + (s >> 2) * 16 + quad * 4 + (s & 3);
        const int pos = (colg * 16 + lm) * 2;
        mb[row * 65 + pos] = p1[s];
        mb[row * 65 + pos + 1] = p2[s];
    }
    __syncthreads();
    if (tid < 128) {
        float t1 = -INFINITY, t2 = -INFINITY, t3 = -INFINITY, t4 = -INFINITY;
        for (int p = 0; p < 64; ++p) {
            const float v = mb[tid * 65 + p];
            const float m1 = fminf(t1, v);
            t1 = fmaxf(t1, v);
            const float m2 = fminf(t2, m1);
            t2 = fmaxf(t2, m1);
            const float m3 = fminf(t3, m2);
            t3 = fmaxf(t3, m2);
            t4 = fmaxf(t4, m3);
        }
        top4s[tid][0] = t1; top4s[tid][1] = t2; top4s[tid][2] = t3; top4s[tid][3] = t4;
    }
    __syncthreads();

    // ---- exact fp32 recheck: 4 threads/row, 1 candidate each ----
    {
        const int row = tid >> 2;
        const int ci = tid & 3;
        const int k = (int)(__float_as_uint(top4s[row][ci]) & 8191u);
        const float4* x4 = (const float4*)(x + (size_t)(rowblk + row) * DIM);
        float cs[4];
#pragma unroll
        for (int co = 0; co < 4; ++co) {
            float s = 0.f;
            for (int c4 = 0; c4 < 16; ++c4) {
                const float4 v = x4[co * 16 + c4];
                s = fmaf(v.x, v.x, s); s = fmaf(v.y, v.y, s);
                s = fmaf(v.z, v.z, s); s = fmaf(v.w, v.w, s);
            }
            cs[co] = s;
        }
        const float xsq = ((cs[0] + cs[1]) + cs[2]) + cs[3];
        const float4* e4 = (const float4*)(embed + (size_t)k * DIM);
        float dot = 0.f, es = 0.f;
        for (int c4 = 0; c4 < 64; ++c4) {
            const float4 xv = x4[c4], evv = e4[c4];
            dot = fmaf(xv.x, evv.x, dot); dot = fmaf(xv.y, evv.y, dot);
            dot = fmaf(xv.z, evv.z, dot); dot = fmaf(xv.w, evv.w, dot);
            es = fmaf(evv.x, evv.x, es); es = fmaf(evv.y, evv.y, es);
            es = fmaf(evv.z, evv.z, es); es = fmaf(evv.w, evv.w, es);
        }
        rd[row][ci] = fmaf(-2.0f, dot, xsq) + es;   // validated rounding sequence
        rk[row][ci] = k;
    }
    __syncthreads();
    if (tid < 128) {
        float best = rd[tid][0]; int bidx = rk[tid][0];
#pragma unroll
        for (int t = 1; t < 4; ++t) {
            const float d2 = rd[tid][t]; const int k2 = rk[tid][t];
            if (d2 < best || (d2 == best && k2 < bidx)) { best = d2; bidx = k2; }
        }
        win[tid] = bidx;
    }
    __syncthreads();

    // ---- coalesced gather ----
    {
        const int q = tid & 63;
        const int rb = tid >> 6;
        const float4* e4 = (const float4*)embed;
        float4* o4 = (float4*)out;
#pragma unroll
        for (int p = 0; p < 16; ++p) {
            const int r = rb + p * 8;
            const int k = win[r];
            o4[(size_t)(rowblk + r) * 64 + q] = e4[(size_t)k * 64 + q];
        }
    }
#undef PHASE
#undef COMPUTE_TILE
#undef ISSUE_PKT
}

// ---------------- Fallback (round-1 kernel, passed absmax 0) ----------------
#define BM 64
#define BN 128
#define BC 64
#define NKT (KCODES / BN)
#define NCC (DIM / BC)

__global__ __launch_bounds__(256, 3) void vq_argmin_gather(
    const float* __restrict__ x, const float* __restrict__ embed,
    float* __restrict__ out)
{
    __shared__ __align__(16) float xs[BC * BM];
    __shared__ __align__(16) float es[BC * BN];
    const int tid = threadIdx.x;
    const int tx = tid & 15;
    const int ty = tid >> 4;
    const int row0 = blockIdx.x * BM;
    float xsq[4];
    {
        const int m = tid >> 2;
        const int quarter = tid & 3;
        const float* xr = x + (size_t)(row0 + m) * DIM + quarter * 64;
        float s = 0.f;
        for (int c = 0; c < 64; ++c) s = fmaf(xr[c], xr[c], s);
        es[tid] = s;
        __syncthreads();
#pragma unroll
        for (int i = 0; i < 4; ++i) {
            const int r = 4 * ty + i;
            xsq[i] = ((es[4*r] + es[4*r+1]) + es[4*r+2]) + es[4*r+3];
        }
        __syncthreads();
    }
    float bd[4] = {INFINITY, INFINITY, INFINITY, INFINITY};
    int bk[4] = {0, 0, 0, 0};
    for (int kt = 0; kt < NKT; ++kt) {
        const int k0 = kt * BN;
        float acc[4][8];
#pragma unroll
        for (int i = 0; i < 4; ++i)
#pragma unroll
            for (int j = 0; j < 8; ++j) acc[i][j] = 0.f;
        float e_acc = 0.f;
        for (int cc = 0; cc < NCC; ++cc) {
            __syncthreads();
            {
                const int q = tid & 15;
                const int nb = tid >> 4;
#pragma unroll
                for (int p = 0; p < 4; ++p) {
                    const int m = nb + 16 * p;
                    const float4 v = *(const float4*)(x + (size_t)(row0 + m) * DIM + cc * BC + 4 * q);
                    xs[(4*q+0)*BM+m] = v.x; xs[(4*q+1)*BM+m] = v.y;
                    xs[(4*q+2)*BM+m] = v.z; xs[(4*q+3)*BM+m] = v.w;
                }
#pragma unroll
                for (int p = 0; p < 8; ++p) {
                    const int n = nb + 16 * p;
                    const float4 v = *(const float4*)(embed + (size_t)(k0 + n) * DIM + cc * BC + 4 * q);
                    es[(4*q+0)*BN+n] = v.x; es[(4*q+1)*BN+n] = v.y;
                    es[(4*q+2)*BN+n] = v.z; es[(4*q+3)*BN+n] = v.w;
                }
            }
            __syncthreads();
            if (tid < BN) {
#pragma unroll 8
                for (int c = 0; c < BC; ++c) { const float v = es[c*BN+tid]; e_acc = fmaf(v, v, e_acc); }
            }
#pragma unroll 8
            for (int c = 0; c < BC; ++c) {
                const float4 a0 = *(const float4*)&xs[c*BM+4*ty];
                const float4 b0 = *(const float4*)&es[c*BN+4*tx];
                const float4 b1 = *(const float4*)&es[c*BN+64+4*tx];
                const float a[4] = {a0.x, a0.y, a0.z, a0.w};
                const float b[8] = {b0.x, b0.y, b0.z, b0.w, b1.x, b1.y, b1.z, b1.w};
#pragma unroll
                for (int i = 0; i < 4; ++i)
#pragma unroll
                    for (int j = 0; j < 8; ++j) acc[i][j] = fmaf(a[i], b[j], acc[i][j]);
            }
        }
        __syncthreads();
        if (tid < BN) es[tid] = e_acc;
        __syncthreads();
        float esq2[8];
#pragma unroll
        for (int j = 0; j < 4; ++j) { esq2[j] = es[4*tx+j]; esq2[4+j] = es[64+4*tx+j]; }
#pragma unroll
        for (int i = 0; i < 4; ++i)
#pragma unroll
            for (int j = 0; j < 8; ++j) {
                const float d = fmaf(-2.0f, acc[i][j], xsq[i]) + esq2[j];
                const int kk = k0 + ((j < 4) ? (4*tx+j) : (64+4*tx+(j-4)));
                if (d < bd[i]) { bd[i] = d; bk[i] = kk; }
            }
    }
    __syncthreads();
    float* red_d = xs;
    int* red_k = (int*)es;
#pragma unroll
    for (int i = 0; i < 4; ++i) { const int r = 4*ty+i; red_d[r*16+tx] = bd[i]; red_k[r*16+tx] = bk[i]; }
    __syncthreads();
    int winner = 0;
    if (tid < BM) {
        float best = red_d[tid*16]; int bidx = red_k[tid*16];
#pragma unroll
        for (int t = 1; t < 16; ++t) {
            const float d2 = red_d[tid*16+t]; const int k2 = red_k[tid*16+t];
            if (d2 < best || (d2 == best && k2 < bidx)) { best = d2; bidx = k2; }
        }
        winner = bidx;
    }
    __syncthreads();
    int* wn = (int*)xs;
    if (tid < BM) wn[tid] = winner;
    __syncthreads();
    {
        const int q = tid & 63;
        const int rb = tid >> 6;
        const float4* e4 = (const float4*)embed;
        float4* o4 = (float4*)out;
#pragma unroll
        for (int p = 0; p < 16; ++p) {
            const int rr = rb + 4 * p;
            const int k = wn[rr];
            o4[(size_t)(row0 + rr) * 64 + q] = e4[(size_t)k * 64 + q];
        }
    }
}

extern "C" void kernel_launch(void* const* d_in, const int* in_sizes, int n_in,
                              void* d_out, int out_size, void* d_ws, size_t ws_size,
                              hipStream_t stream) {
    const float* x = (const float*)d_in[0];
    const float* embed = (const float*)d_in[1];
    float* out = (float*)d_out;

    if (ws_size < (size_t)WS_NEED) {
        hipLaunchKernelGGL(vq_argmin_gather, dim3(NROWS / BM), dim3(256), 0, stream, x, embed, out);
        return;
    }
    char* ws = (char*)d_ws;
    _Float16* Es = (_Float16*)(ws + ES_OFF);
    float* esq = (float*)(ws + ESQ_OFF);

    hipLaunchKernelGGL(cvt_esq, dim3(128), dim3(256), 0, stream, embed, Es, esq);
    hipLaunchKernelGGL(vq_fused, dim3(256), dim3(512), 0, stream, x, Es, esq, embed, out);
}